// Round 7
// baseline (452.113 us; speedup 1.0000x reference)
//
#include <hip/hip_runtime.h>
#include <hip/hip_bf16.h>
#include <cstdint>

// H=8, T=2048, E=512. Inputs/outputs FLOAT32; bf16 intermediates.
// All GEMMs NT: C[m][n] = sum_k A[m][k]*B[n][k]  (A:[MxK] lda, B:[NxK] ldb).
//
// Engines:
//  1) gemm256_8ph: 256x256 tile, 8 waves, BK=64, 8-phase counted-vmcnt schedule
//     (T2+T3+T4+T5), 128 KB LDS dbuf. Used ONLY for QK^T (512 wgs).
//  2) mfma_gemm_nt: 128x128 tile, 8 waves, BK=64, 2-phase dbuf, 64 KB LDS.
//     Used for q/k/v projections and PV.
//  3) gemm_f32a_k32 (NEW r7): 128x128 tile, 8 waves, BK=32, 2-phase dbuf,
//     32 KB LDS, __launch_bounds__(512,8) -> 4 blocks/CU. f32-A reg-staged
//     (T14 split), bf16-B via global_load_lds. Used for the final Wf GEMM with
//     split-K=16 (grid 1024): same 32 phases/wg as split8/BK64 but 2x the
//     resident waves to hide the 2-phase barrier drain (r6: occupancy 38.6%,
//     MfmaUtil 17% -> latency-bound).
// All: LDS XOR chunk-swizzle both-sides (rule #21), T1 XCD-bijective swizzle.
//
// Pipeline:
//   fused_cvt: xb/yb/zb/Wqb/Wkb/Wvb <- bf16 converts (single launch)
//   q_all[T][H*E] = x Wq_cat^T + bq ; k_all likewise   (2ph engine)
//   vT[H*E][T]    = Wv_cat z^T + bv                    (2ph engine)
//   att[h]=softmax(q k^T / sqrt(T))                    (gemm256_8ph z=8; bf16x8 softmax)
//   hoT[f][h*T+s]=sum_t vT[h][f][t] att[h][s][t]       (2ph engine)
//   fin_parts[z][t][e] = Wf[t][zK:+K] . hoT[e][zK:+K]  (split-K=16, disjoint, f32a_k32)
//   out = LN(sum_z fin_parts + bf[t] + z)              (16-way reduce in ln_res)

#define HH 8
#define TT 2048
#define EE 512
#define HT (HH * TT)
#define HE (HH * EE)

typedef __bf16 bf16_t;
typedef __attribute__((ext_vector_type(8))) __bf16 bf16x8;
typedef __attribute__((ext_vector_type(4))) float f32x4;

__device__ __forceinline__ void gld_lds16(const bf16_t* __restrict__ g, bf16_t* l) {
  __builtin_amdgcn_global_load_lds(
      (const __attribute__((address_space(1))) unsigned int*)g,
      (__attribute__((address_space(3))) unsigned int*)l, 16, 0, 0);
}

__device__ __forceinline__ bf16x8 cvt8(float4 u, float4 v) {
  bf16x8 o;
  o[0] = (__bf16)u.x; o[1] = (__bf16)u.y; o[2] = (__bf16)u.z; o[3] = (__bf16)u.w;
  o[4] = (__bf16)v.x; o[5] = (__bf16)v.y; o[6] = (__bf16)v.z; o[7] = (__bf16)v.w;
  return o;
}

// T1 XCD-bijective swizzle (m204): decode (bx,by,z) from remapped linear id.
#define XCD_SWIZZLE()                                                              \
  const int gx = gridDim.x, gy = gridDim.y;                                        \
  const int nwg = gx * gy * (int)gridDim.z;                                        \
  const int lin = blockIdx.x + gx * (blockIdx.y + gy * blockIdx.z);                \
  const int qn_ = nwg >> 3, rn_ = nwg & 7;                                         \
  const int xcd_ = lin & 7, sub_ = lin >> 3;                                       \
  const int wgid =                                                                 \
      (xcd_ < rn_ ? xcd_ * (qn_ + 1) : rn_ * (qn_ + 1) + (xcd_ - rn_) * qn_) + sub_; \
  const int bx = wgid % gx;                                                        \
  const int t1_ = wgid / gx;                                                       \
  const int by = t1_ % gy;                                                         \
  const int z = t1_ / gy;

// =====================================================================
// 256x256 8-phase GEMM (bf16 A,B). grid (M/256, N/256, nz), 512 threads.
// K % 128 == 0. Per-z: A += z*sA, B += z*sB, C += z*sC, bias_n += z*sBN.
// =====================================================================
template <typename CT>
__global__ __launch_bounds__(512, 2) void gemm256_8ph(
    const bf16_t* __restrict__ A, const bf16_t* __restrict__ B, CT* __restrict__ C,
    const float* __restrict__ bias_n,
    int K, int lda, int ldb, int ldc,
    int64_t sA, int64_t sB, int64_t sC, int64_t sBN) {
  XCD_SWIZZLE();
  A += z * sA;
  B += z * sB;
  C += z * sC;
  if (bias_n) bias_n += z * sBN;

  const int m0 = bx * 256;
  const int n0 = by * 256;
  const int tid = threadIdx.x;

  // [A|B][2 buf][2 half][128 rows][64 cols] bf16 = 128 KB total.
  __shared__ bf16_t lds[65536];
  bf16_t* sAl = lds;           // 32768 elems: buf*16384 + half*8192 + row*64 + col
  bf16_t* sBl = lds + 32768;

  const int srow = tid >> 3;
  const int csw = ((tid & 7) ^ (srow & 7)) * 8;  // swizzled source col (elems)
  const bf16_t* aS = A + (int64_t)(m0 + srow) * lda + csw;
  const bf16_t* bS = B + (int64_t)(n0 + srow) * ldb + csw;
  const int64_t l64a = (int64_t)64 * lda, l64b = (int64_t)64 * ldb;

  const int wave = tid >> 6, lane = tid & 63;
  const int wr = wave >> 2, wc = wave & 3;
  const int fr = lane & 15, qd = lane >> 4;
  const int aoff = wr * 8192 + fr * 64;
  const int boff = wc * 4096 + fr * 64;
  const int ck0 = ((0 * 4 + qd) ^ (fr & 7)) * 8;
  const int ck1 = ((1 * 4 + qd) ^ (fr & 7)) * 8;

  f32x4 acc[8][4];
#pragma unroll
  for (int i = 0; i < 8; i++)
#pragma unroll
    for (int j = 0; j < 4; j++) acc[i][j] = (f32x4){0.f, 0.f, 0.f, 0.f};

  bf16x8 aR[2][8];
  bf16x8 bR[2][2];

#define STG_A(d, h, t)                                                        \
  do {                                                                        \
    const bf16_t* g_ = aS + (int64_t)(h) * 128 * lda + (int64_t)(t) * 64;     \
    gld_lds16(g_, &sAl[(d) * 16384 + (h) * 8192 + tid * 8]);                  \
    gld_lds16(g_ + l64a, &sAl[(d) * 16384 + (h) * 8192 + 4096 + tid * 8]);    \
  } while (0)
#define STG_B(d, h, t)                                                        \
  do {                                                                        \
    const bf16_t* g_ = bS + (int64_t)(h) * 128 * ldb + (int64_t)(t) * 64;     \
    gld_lds16(g_, &sBl[(d) * 16384 + (h) * 8192 + tid * 8]);                  \
    gld_lds16(g_ + l64b, &sBl[(d) * 16384 + (h) * 8192 + 4096 + tid * 8]);    \
  } while (0)
#define RD_A(d, ih)                                                           \
  _Pragma("unroll") for (int i_ = 0; i_ < 4; i_++) {                          \
    const int b_ = (d) * 16384 + aoff + ((ih) * 4 + i_) * 1024;               \
    aR[0][(ih) * 4 + i_] = *(const bf16x8*)&sAl[b_ + ck0];                    \
    aR[1][(ih) * 4 + i_] = *(const bf16x8*)&sAl[b_ + ck1];                    \
  }
#define RD_B(d, jh)                                                           \
  _Pragma("unroll") for (int j_ = 0; j_ < 2; j_++) {                          \
    const int b_ = (d) * 16384 + boff + ((jh) * 2 + j_) * 1024;               \
    bR[0][j_] = *(const bf16x8*)&sBl[b_ + ck0];                               \
    bR[1][j_] = *(const bf16x8*)&sBl[b_ + ck1];                               \
  }
#define MM(qm, qn)                                                            \
  do {                                                                        \
    __builtin_amdgcn_s_setprio(1);                                            \
    _Pragma("unroll") for (int ks = 0; ks < 2; ks++)                          \
        _Pragma("unroll") for (int i_ = 0; i_ < 4; i_++)                      \
            _Pragma("unroll") for (int j_ = 0; j_ < 2; j_++)                  \
                acc[(qm) * 4 + i_][(qn) * 2 + j_] =                           \
                    __builtin_amdgcn_mfma_f32_16x16x32_bf16(                  \
                        aR[ks][(qm) * 4 + i_], bR[ks][j_],                    \
                        acc[(qm) * 4 + i_][(qn) * 2 + j_], 0, 0, 0);          \
    __builtin_amdgcn_s_setprio(0);                                            \
  } while (0)
#define BAR __builtin_amdgcn_s_barrier()
#define LGKM0                                                                 \
  do {                                                                        \
    asm volatile("s_waitcnt lgkmcnt(0)" ::: "memory");                        \
    __builtin_amdgcn_sched_barrier(0);                                        \
  } while (0)
#define VMC(n)                                                                \
  do {                                                                        \
    asm volatile("s_waitcnt vmcnt(" #n ")" ::: "memory");                     \
    __builtin_amdgcn_sched_barrier(0);                                        \
  } while (0)

  const int NT = K >> 6;

  STG_A(0, 0, 0); STG_A(0, 1, 0); STG_B(0, 0, 0); STG_B(0, 1, 0);
  STG_A(1, 0, 1); STG_A(1, 1, 1);
  VMC(4);
  BAR;

  for (int t0 = 0; t0 < NT; t0 += 2) {
    const int t1 = t0 + 1;
    const bool m2 = (t0 + 2) < NT;
    RD_A(0, 0); RD_B(0, 0);
    STG_B(1, 0, t1);
    BAR; LGKM0; MM(0, 0); BAR;
    RD_A(0, 1);
    STG_B(1, 1, t1);
    BAR; LGKM0; MM(1, 0); BAR;
    RD_B(0, 1);
    if (m2) STG_A(0, 0, t0 + 2);
    BAR; LGKM0; MM(0, 1); BAR;
    if (m2) STG_A(0, 1, t0 + 2);
    BAR; MM(1, 1);
    if (m2) { VMC(4); } else { VMC(0); }
    BAR;
    RD_A(1, 0); RD_B(1, 0);
    if (m2) STG_B(0, 0, t0 + 2);
    BAR; LGKM0; MM(0, 0); BAR;
    RD_A(1, 1);
    if (m2) STG_B(0, 1, t0 + 2);
    BAR; LGKM0; MM(1, 0); BAR;
    RD_B(1, 1);
    if (m2) STG_A(1, 0, t1 + 2);
    BAR; LGKM0; MM(0, 1); BAR;
    if (m2) STG_A(1, 1, t1 + 2);
    BAR; MM(1, 1);
    if (m2) VMC(4);
    BAR;
  }

#undef STG_A
#undef STG_B
#undef RD_A
#undef RD_B
#undef MM
#undef BAR
#undef LGKM0
#undef VMC

#pragma unroll
  for (int i = 0; i < 8; i++) {
    const int row0 = m0 + wr * 128 + i * 16 + qd * 4;
#pragma unroll
    for (int j = 0; j < 4; j++) {
      const int col = n0 + wc * 64 + j * 16 + fr;
      const float bn = bias_n ? bias_n[col] : 0.f;
#pragma unroll
      for (int r = 0; r < 4; r++)
        C[(int64_t)(row0 + r) * ldc + col] = (CT)(acc[i][j][r] + bn);
    }
  }
}

// =====================================================================
// 128x128 2-phase dbuf GEMM, bf16 A/B. grid (M/128, N/128, nz), 512 threads.
// K % 128 == 0.
// =====================================================================
template <typename AT, typename CT>
__global__ __launch_bounds__(512, 4) void mfma_gemm_nt(
    const AT* __restrict__ A, const bf16_t* __restrict__ B, CT* __restrict__ C,
    const float* __restrict__ bias_m, const float* __restrict__ bias_n,
    int K, int lda, int ldb, int ldc,
    int64_t sA, int64_t sB, int64_t sC, int64_t sBM, int64_t sBN) {
  XCD_SWIZZLE();
  A += z * sA;
  B += z * sB;
  C += z * sC;
  if (bias_m) bias_m += z * sBM;
  if (bias_n) bias_n += z * sBN;

  const int m0 = bx * 128;
  const int n0 = by * 128;
  const int tid = threadIdx.x;

  __shared__ bf16_t sAb[2][128 * 64];
  __shared__ bf16_t sBb[2][128 * 64];

  const int srow = tid >> 3;
  const int sc = tid & 7;
  const int csw = (sc ^ (srow & 7)) * 8;
  const AT* a0 = A + (int64_t)(m0 + srow) * lda + csw;
  const AT* a1 = a0 + (int64_t)64 * lda;
  const bf16_t* b0 = B + (int64_t)(n0 + srow) * ldb + csw;
  const bf16_t* b1 = b0 + (int64_t)64 * ldb;

  const int wave = tid >> 6;
  const int lane = tid & 63;
  const int wm = (wave >> 2) * 64;
  const int wn = (wave & 3) * 32;
  const int fr = lane & 15;
  const int qd = lane >> 4;
  const int cx0 = ((0 * 4 + qd) ^ (fr & 7)) * 8;
  const int cx1 = ((1 * 4 + qd) ^ (fr & 7)) * 8;

  f32x4 acc[4][2];
#pragma unroll
  for (int i = 0; i < 4; i++)
#pragma unroll
    for (int j = 0; j < 2; j++) acc[i][j] = (f32x4){0.f, 0.f, 0.f, 0.f};

  float4 pa[4];

#define STAGE_B(buf, kt)                              \
  do {                                                \
    gld_lds16(b0 + (kt), &sBb[buf][tid * 8]);         \
    gld_lds16(b1 + (kt), &sBb[buf][4096 + tid * 8]);  \
  } while (0)
#define STAGE_A_BF16(buf, kt)                         \
  do {                                                \
    gld_lds16(a0 + (kt), &sAb[buf][tid * 8]);         \
    gld_lds16(a1 + (kt), &sAb[buf][4096 + tid * 8]);  \
  } while (0)
#define LOAD_A_F32(kt)                                \
  do {                                                \
    pa[0] = ((const float4*)(a0 + (kt)))[0];          \
    pa[1] = ((const float4*)(a0 + (kt)))[1];          \
    pa[2] = ((const float4*)(a1 + (kt)))[0];          \
    pa[3] = ((const float4*)(a1 + (kt)))[1];          \
  } while (0)
#define WRITE_A_F32(buf)                                      \
  do {                                                        \
    *(bf16x8*)&sAb[buf][tid * 8] = cvt8(pa[0], pa[1]);        \
    *(bf16x8*)&sAb[buf][4096 + tid * 8] = cvt8(pa[2], pa[3]); \
  } while (0)
#define COMPUTE(buf)                                                                   \
  do {                                                                                 \
    bf16x8 af[2][4], bfr[2][2];                                                        \
    _Pragma("unroll") for (int i = 0; i < 4; i++) {                                    \
      const int ar = (wm + i * 16 + fr) * 64;                                          \
      af[0][i] = *(const bf16x8*)&sAb[buf][ar + cx0];                                  \
      af[1][i] = *(const bf16x8*)&sAb[buf][ar + cx1];                                  \
    }                                                                                  \
    _Pragma("unroll") for (int j = 0; j < 2; j++) {                                    \
      const int br = (wn + j * 16 + fr) * 64;                                          \
      bfr[0][j] = *(const bf16x8*)&sBb[buf][br + cx0];                                 \
      bfr[1][j] = *(const bf16x8*)&sBb[buf][br + cx1];                                 \
    }                                                                                  \
    _Pragma("unroll") for (int ks = 0; ks < 2; ks++)                                   \
        _Pragma("unroll") for (int i = 0; i < 4; i++)                                  \
            _Pragma("unroll") for (int j = 0; j < 2; j++)                              \
                acc[i][j] = __builtin_amdgcn_mfma_f32_16x16x32_bf16(                   \
                    af[ks][i], bfr[ks][j], acc[i][j], 0, 0, 0);                        \
  } while (0)

  if constexpr (sizeof(AT) == 2) {
    STAGE_A_BF16(0, 0);
  } else {
    LOAD_A_F32(0);
    WRITE_A_F32(0);
  }
  STAGE_B(0, 0);
  __syncthreads();

  for (int kt = 0; kt < K; kt += 128) {
    if constexpr (sizeof(AT) == 2) {
      STAGE_A_BF16(1, kt + 64);
    } else {
      LOAD_A_F32(kt + 64);
    }
    STAGE_B(1, kt + 64);
    COMPUTE(0);
    if constexpr (sizeof(AT) == 4) WRITE_A_F32(1);
    __syncthreads();

    const bool more = (kt + 128) < K;
    if (more) {
      if constexpr (sizeof(AT) == 2) {
        STAGE_A_BF16(0, kt + 128);
      } else {
        LOAD_A_F32(kt + 128);
      }
      STAGE_B(0, kt + 128);
    }
    COMPUTE(1);
    if constexpr (sizeof(AT) == 4) {
      if (more) WRITE_A_F32(0);
    }
    __syncthreads();
  }

#undef STAGE_B
#undef STAGE_A_BF16
#undef LOAD_A_F32
#undef WRITE_A_F32
#undef COMPUTE

#pragma unroll
  for (int i = 0; i < 4; i++) {
    const int row0 = m0 + wm + i * 16 + qd * 4;
#pragma unroll
    for (int j = 0; j < 2; j++) {
      const int col = n0 + wn + j * 16 + fr;
      const float bn = bias_n ? bias_n[col] : 0.f;
#pragma unroll
      for (int r = 0; r < 4; r++) {
        const float bm = bias_m ? bias_m[row0 + r] : 0.f;
        C[(int64_t)(row0 + r) * ldc + col] = (CT)(acc[i][j][r] + bn + bm);
      }
    }
  }
}

// =====================================================================
// NEW (r7): 128x128 2-phase dbuf GEMM, f32 A (reg-staged) + bf16 B, BK=32,
// 32 KB LDS, __launch_bounds__(512,8) -> 4 blocks/CU at grid >= 1024.
// grid (M/128, N/128, nz), K % 64 == 0. No biases (final GEMM has none).
// XOR swizzle: 4 chunks/row, involution chunk ^= (row&3), both sides.
// =====================================================================
__global__ __launch_bounds__(512, 8) void gemm_f32a_k32(
    const float* __restrict__ A, const bf16_t* __restrict__ B, float* __restrict__ C,
    int K, int lda, int ldb, int ldc, int64_t sA, int64_t sB, int64_t sC) {
  XCD_SWIZZLE();
  A += z * sA;
  B += z * sB;
  C += z * sC;

  const int m0 = bx * 128;
  const int n0 = by * 128;
  const int tid = threadIdx.x;

  __shared__ bf16_t sAb[2][128 * 32];  // 2 x 8 KB
  __shared__ bf16_t sBb[2][128 * 32];  // 2 x 8 KB  (32 KB total)

  // staging: 512 threads cover one 128x32 tile (8 elems each).
  // row = tid>>2, chunk sc = tid&3; LDS chunk sc of row r holds GLOBAL chunk sc^(r&3).
  const int srow = tid >> 2;
  const int csw = ((tid & 3) ^ (srow & 3)) * 8;
  const float* a0 = A + (int64_t)(m0 + srow) * lda + csw;
  const bf16_t* b0 = B + (int64_t)(n0 + srow) * ldb + csw;

  const int wave = tid >> 6;
  const int lane = tid & 63;
  const int wm = (wave >> 2) * 64;
  const int wn = (wave & 3) * 32;
  const int fr = lane & 15;
  const int qd = lane >> 4;                 // k-chunk 0..3
  const int ck = (qd ^ (fr & 3)) * 8;       // swizzled read chunk

  f32x4 acc[4][2];
#pragma unroll
  for (int i = 0; i < 4; i++)
#pragma unroll
    for (int j = 0; j < 2; j++) acc[i][j] = (f32x4){0.f, 0.f, 0.f, 0.f};

  float4 pa[2];

#define STAGE_B32(buf, kt) gld_lds16(b0 + (kt), &sBb[buf][tid * 8])
#define LOAD_A32(kt)                                \
  do {                                              \
    pa[0] = ((const float4*)(a0 + (kt)))[0];        \
    pa[1] = ((const float4*)(a0 + (kt)))[1];        \
  } while (0)
#define WRITE_A32(buf) *(bf16x8*)&sAb[buf][tid * 8] = cvt8(pa[0], pa[1])
#define COMPUTE32(buf)                                                                 \
  do {                                                                                 \
    bf16x8 af[4], bfr[2];                                                              \
    _Pragma("unroll") for (int i = 0; i < 4; i++)                                      \
        af[i] = *(const bf16x8*)&sAb[buf][(wm + i * 16 + fr) * 32 + ck];               \
    _Pragma("unroll") for (int j = 0; j < 2; j++)                                      \
        bfr[j] = *(const bf16x8*)&sBb[buf][(wn + j * 16 + fr) * 32 + ck];              \
    _Pragma("unroll") for (int i = 0; i < 4; i++)                                      \
        _Pragma("unroll") for (int j = 0; j < 2; j++)                                  \
            acc[i][j] = __builtin_amdgcn_mfma_f32_16x16x32_bf16(                       \
                af[i], bfr[j], acc[i][j], 0, 0, 0);                                    \
  } while (0)

  LOAD_A32(0);
  WRITE_A32(0);
  STAGE_B32(0, 0);
  __syncthreads();

  for (int kt = 0; kt < K; kt += 64) {
    LOAD_A32(kt + 32);
    STAGE_B32(1, kt + 32);
    COMPUTE32(0);
    WRITE_A32(1);
    __syncthreads();

    const bool more = (kt + 64) < K;
    if (more) {
      LOAD_A32(kt + 64);
      STAGE_B32(0, kt + 64);
    }
    COMPUTE32(1);
    if (more) WRITE_A32(0);
    __syncthreads();
  }

#undef STAGE_B32
#undef LOAD_A32
#undef WRITE_A32
#undef COMPUTE32

#pragma unroll
  for (int i = 0; i < 4; i++) {
    const int row0 = m0 + wm + i * 16 + qd * 4;
#pragma unroll
    for (int j = 0; j < 2; j++) {
      const int col = n0 + wn + j * 16 + fr;
#pragma unroll
      for (int r = 0; r < 4; r++)
        C[(int64_t)(row0 + r) * ldc + col] = acc[i][j][r];
    }
  }
}

// ---------- fused f32 -> bf16 convert: x,y,z,Wq,Wk,Wv in ONE launch ----------
__global__ __launch_bounds__(256) void fused_cvt(
    const float* __restrict__ x, const float* __restrict__ y,
    const float* __restrict__ z, const float* __restrict__ Wq,
    const float* __restrict__ Wk, const float* __restrict__ Wv,
    bf16_t* __restrict__ xb, bf16_t* __restrict__ yb, bf16_t* __restrict__ zb,
    bf16_t* __restrict__ Wqb, bf16_t* __restrict__ Wkb, bf16_t* __restrict__ Wvb) {
  const int b = blockIdx.x;
  const float* s;
  bf16_t* d;
  int off;
  if (b < 512) { s = x; d = xb; off = b; }
  else if (b < 1024) { s = y; d = yb; off = b - 512; }
  else if (b < 1536) { s = z; d = zb; off = b - 1024; }
  else if (b < 2560) { s = Wq; d = Wqb; off = b - 1536; }
  else if (b < 3584) { s = Wk; d = Wkb; off = b - 2560; }
  else { s = Wv; d = Wvb; off = b - 3584; }
  const int64_t i = ((int64_t)off * 256 + threadIdx.x) * 8;
  float4 u = ((const float4*)(s + i))[0];
  float4 v = ((const float4*)(s + i))[1];
  *(bf16x8*)(d + i) = cvt8(u, v);
}

// ---------- in-place row softmax (rows of length T), 1/sqrt(T) pre-scale ----------
__global__ __launch_bounds__(256) void softmax_rows(bf16_t* __restrict__ S) {
  const float scale = 0.022097086912079608f;  // 1/sqrt(2048)
  bf16_t* p = S + (int64_t)blockIdx.x * TT;
  const int tid = threadIdx.x;
  bf16x8 in = *(const bf16x8*)(p + tid * 8);
  float v[8];
  float mx = -1e30f;
#pragma unroll
  for (int i = 0; i < 8; i++) {
    v[i] = (float)in[i] * scale;
    mx = fmaxf(mx, v[i]);
  }
#pragma unroll
  for (int o = 32; o > 0; o >>= 1) mx = fmaxf(mx, __shfl_xor(mx, o));
  __shared__ float redm[4], reds[4];
  if ((tid & 63) == 0) redm[tid >> 6] = mx;
  __syncthreads();
  mx = fmaxf(fmaxf(redm[0], redm[1]), fmaxf(redm[2], redm[3]));
  float sum = 0.f;
#pragma unroll
  for (int i = 0; i < 8; i++) {
    v[i] = __expf(v[i] - mx);
    sum += v[i];
  }
#pragma unroll
  for (int o = 32; o > 0; o >>= 1) sum += __shfl_xor(sum, o);
  if ((tid & 63) == 0) reds[tid >> 6] = sum;
  __syncthreads();
  sum = reds[0] + reds[1] + reds[2] + reds[3];
  const float inv = 1.0f / sum;
  bf16x8 o8;
#pragma unroll
  for (int i = 0; i < 8; i++) o8[i] = (__bf16)(v[i] * inv);
  *(bf16x8*)(p + tid * 8) = o8;
}

// ---------- out = LN(sum_{pz<np} fin_parts + bf[t] + z), eps=1e-4, population var ----
__global__ __launch_bounds__(256) void ln_res(const float* __restrict__ F,
                                              const float* __restrict__ Z,
                                              const float* __restrict__ BF,
                                              float* __restrict__ O, int np) {
  const int row = blockIdx.x;
  const int tid = threadIdx.x;
  const int64_t off = (int64_t)row * EE + tid;
  float a = 0.f, b = 0.f;
  for (int pz = 0; pz < np; pz++) {
    const float* f = F + (int64_t)pz * TT * EE;
    a += f[off];
    b += f[off + 256];
  }
  const float bft = BF[row];
  a += bft + Z[off];
  b += bft + Z[off + 256];
  float s = a + b, ss = a * a + b * b;
#pragma unroll
  for (int w = 32; w > 0; w >>= 1) {
    s += __shfl_xor(s, w);
    ss += __shfl_xor(ss, w);
  }
  __shared__ float rs[4], rss[4];
  if ((tid & 63) == 0) {
    rs[tid >> 6] = s;
    rss[tid >> 6] = ss;
  }
  __syncthreads();
  s = rs[0] + rs[1] + rs[2] + rs[3];
  ss = rss[0] + rss[1] + rss[2] + rss[3];
  const float mean = s * (1.0f / EE);
  const float var = ss * (1.0f / EE) - mean * mean;
  const float inv = rsqrtf(var + 1e-4f);
  float* o = O + (int64_t)row * EE;
  o[tid] = (a - mean) * inv;
  o[tid + 256] = (b - mean) * inv;
}

extern "C" void kernel_launch(void* const* d_in, const int* in_sizes, int n_in,
                              void* d_out, int out_size, void* d_ws, size_t ws_size,
                              hipStream_t stream) {
  const float* x = (const float*)d_in[0];
  const float* y = (const float*)d_in[1];
  const float* z = (const float*)d_in[2];
  const float* Wq = (const float*)d_in[3];
  const float* bq = (const float*)d_in[4];
  const float* Wk = (const float*)d_in[5];
  const float* bk = (const float*)d_in[6];
  const float* Wv = (const float*)d_in[7];
  const float* bv = (const float*)d_in[8];
  const float* Wf = (const float*)d_in[9];
  const float* bfb = (const float*)d_in[10];
  float* out = (float*)d_out;

  const size_t MB = 1ull << 20;
  char* p = (char*)d_ws;

  if (ws_size >= 151 * MB) {
    // ---- FULL layout (head-batched) ----
    bf16_t* xb = (bf16_t*)(p + 0 * MB);
    bf16_t* yb = (bf16_t*)(p + 2 * MB);
    bf16_t* zb = (bf16_t*)(p + 4 * MB);
    bf16_t* Wqb = (bf16_t*)(p + 6 * MB);
    bf16_t* Wkb = (bf16_t*)(p + 10 * MB);
    bf16_t* Wvb = (bf16_t*)(p + 14 * MB);
    bf16_t* q = (bf16_t*)(p + 18 * MB);     // [T][H*E]
    bf16_t* k = (bf16_t*)(p + 34 * MB);     // [T][H*E]
    bf16_t* vT = (bf16_t*)(p + 50 * MB);    // [8][E][T]
    bf16_t* att = (bf16_t*)(p + 66 * MB);   // [8][T][T] (64 MB; dead after hoT)
    bf16_t* hoT = (bf16_t*)(p + 130 * MB);  // [E][H*T] (16 MB, ends 146)
    float* finp = (float*)(p + 66 * MB);    // [16][T][E] f32 (64 MB; overlays dead att)

    fused_cvt<<<4608, 256, 0, stream>>>(x, y, z, Wq, Wk, Wv, xb, yb, zb, Wqb, Wkb, Wvb);

    // q_all[T][HE] = x @ Wq_cat^T + bq_flat  (heads stacked along N)
    mfma_gemm_nt<bf16_t, bf16_t><<<dim3(16, 32, 1), 512, 0, stream>>>(
        xb, Wqb, q, nullptr, bq, EE, EE, EE, HE, 0, 0, 0, 0, 0);
    mfma_gemm_nt<bf16_t, bf16_t><<<dim3(16, 32, 1), 512, 0, stream>>>(
        yb, Wkb, k, nullptr, bk, EE, EE, EE, HE, 0, 0, 0, 0, 0);
    // vT[h*E+f][t] = Wv_cat[h*E+f][:] . z[t][:] + bv_flat  -> [8][E][T]
    mfma_gemm_nt<bf16_t, bf16_t><<<dim3(32, 16, 1), 512, 0, stream>>>(
        Wvb, zb, vT, bv, nullptr, EE, EE, EE, TT, 0, 0, 0, 0, 0);
    // att[h][s][t] = q_all[s][hE:+E] . k_all[t][hE:+E]  (8-phase engine, 512 wgs)
    gemm256_8ph<bf16_t><<<dim3(8, 8, 8), 512, 0, stream>>>(
        q, k, att, nullptr, EE, HE, HE, TT, EE, EE, (int64_t)TT * TT, 0);
    softmax_rows<<<HH * TT, 256, 0, stream>>>(att);
    // hoT[f][h*T+s] = vT[h][f][:] . att[h][s][:]
    mfma_gemm_nt<bf16_t, bf16_t><<<dim3(4, 16, 8), 512, 0, stream>>>(
        vT, att, hoT, nullptr, nullptr, TT, TT, TT, HT, (int64_t)EE * TT, (int64_t)TT * TT,
        (int64_t)TT, 0, 0);
    // fin_parts[z][t][e] = Wf[t][zK:+K] . hoT[e][zK:+K]
    // split-K=16, BK=32 engine: grid 1024 -> 4 blocks/CU (r7 occupancy fix)
    gemm_f32a_k32<<<dim3(16, 4, 16), 512, 0, stream>>>(
        Wf, hoT, finp, HT / 16, HT, HT, EE, HT / 16, HT / 16, (int64_t)TT * EE);
    ln_res<<<TT, 256, 0, stream>>>(finp, z, bfb, out, 16);
  } else {
    // ---- LEAN layout (per-head) ----
    bf16_t* xb = (bf16_t*)(p + 0 * MB);
    bf16_t* yb = (bf16_t*)(p + 2 * MB);
    bf16_t* zb = (bf16_t*)(p + 4 * MB);
    bf16_t* Wqb = (bf16_t*)(p + 6 * MB);
    bf16_t* Wkb = (bf16_t*)(p + 10 * MB);
    bf16_t* Wvb = (bf16_t*)(p + 14 * MB);
    bf16_t* qh = (bf16_t*)(p + 18 * MB);
    bf16_t* kh = (bf16_t*)(p + 20 * MB);
    bf16_t* vTh = (bf16_t*)(p + 22 * MB);
    bf16_t* att = (bf16_t*)(p + 24 * MB);
    bf16_t* hoT = (bf16_t*)(p + 32 * MB);
    float* finp = (float*)(p + 0 * MB);     // [8][T][E] f32 (32 MB; overlays dead bufs)

    fused_cvt<<<4608, 256, 0, stream>>>(x, y, z, Wq, Wk, Wv, xb, yb, zb, Wqb, Wkb, Wvb);

    for (int h = 0; h < HH; h++) {
      const bf16_t* Wq_h = Wqb + (int64_t)h * EE * EE;
      const bf16_t* Wk_h = Wkb + (int64_t)h * EE * EE;
      const bf16_t* Wv_h = Wvb + (int64_t)h * EE * EE;
      mfma_gemm_nt<bf16_t, bf16_t><<<dim3(16, 4, 1), 512, 0, stream>>>(
          xb, Wq_h, qh, nullptr, bq + h * EE, EE, EE, EE, EE, 0, 0, 0, 0, 0);
      mfma_gemm_nt<bf16_t, bf16_t><<<dim3(16, 4, 1), 512, 0, stream>>>(
          yb, Wk_h, kh, nullptr, bk + h * EE, EE, EE, EE, EE, 0, 0, 0, 0, 0);
      mfma_gemm_nt<bf16_t, bf16_t><<<dim3(4, 16, 1), 512, 0, stream>>>(
          Wv_h, zb, vTh, bv + h * EE, nullptr, EE, EE, EE, TT, 0, 0, 0, 0, 0);
      mfma_gemm_nt<bf16_t, bf16_t><<<dim3(16, 16, 1), 512, 0, stream>>>(
          qh, kh, att, nullptr, nullptr, EE, EE, EE, TT, 0, 0, 0, 0, 0);
      softmax_rows<<<TT, 256, 0, stream>>>(att);
      mfma_gemm_nt<bf16_t, bf16_t><<<dim3(4, 16, 1), 512, 0, stream>>>(
          vTh, att, hoT + (int64_t)h * TT, nullptr, nullptr, TT, TT, TT, HT, 0, 0, 0, 0, 0);
    }
    gemm_f32a_k32<<<dim3(16, 4, 8), 512, 0, stream>>>(
        Wf, hoT, finp, HT / 8, HT, HT, EE, HT / 8, HT / 8, (int64_t)TT * EE);
    ln_res<<<TT, 256, 0, stream>>>(finp, z, bfb, out, 8);
  }
}

// Round 8
// 423.897 us; speedup vs baseline: 1.0666x; 1.0666x over previous
//
#include <hip/hip_runtime.h>
#include <hip/hip_bf16.h>
#include <cstdint>

// H=8, T=2048, E=512. Inputs/outputs FLOAT32; bf16 intermediates.
// All GEMMs NT: C[m][n] = sum_k A[m][k]*B[n][k]  (A:[MxK] lda, B:[NxK] ldb).
//
// Engines:
//  1) gemm256_8ph: 256x256 tile, 8 waves, BK=64, 8-phase counted-vmcnt schedule
//     (T2+T3+T4+T5), 128 KB LDS dbuf. Used ONLY for QK^T (512 wgs, verified r4+).
//  2) mfma_gemm_nt (r8: counted-vmcnt upgrade): 128x128 tile, 8 waves, BK=64,
//     2-phase dbuf, 64 KB LDS. T4 applied: raw s_barrier + counted vmcnt —
//     next-tile loads stay in flight ACROSS barriers (never vmcnt(0) in steady
//     state). Ledger: bf16 path 4 vmem/phase -> vmcnt(4); f32-A path 6 vmem/phase
//     -> vmcnt(6) before compute, vmcnt(2) before the A ds_write, lgkmcnt(0)
//     before trailing barrier. Two barriers/phase (read->restage separation).
//     Used for q/k/v projections, PV, and the final Wf GEMM (r6 shape config:
//     f32-A, BK=64, split-K=8 -- r7's BK=32/split-16 regressed: 8-way LDS
//     conflicts (6.3M) + fragmented L2 reuse of Wf).
// All: LDS XOR chunk-swizzle both-sides (rule #21), T1 XCD-bijective swizzle.
//
// Pipeline:
//   fused_cvt: xb/yb/zb/Wqb/Wkb/Wvb <- bf16 converts (single launch)
//   q_all[T][H*E] = x Wq_cat^T + bq ; k_all likewise   (2ph engine)
//   vT[H*E][T]    = Wv_cat z^T + bv                    (2ph engine)
//   att[h]=softmax(q k^T / sqrt(T))                    (gemm256_8ph z=8; bf16x8 softmax)
//   hoT[f][h*T+s]=sum_t vT[h][f][t] att[h][s][t]       (2ph engine)
//   fin_parts[z][t][e] = Wf[t][zK:+K] . hoT[e][zK:+K]  (split-K=8, disjoint)
//   out = LN(sum_z fin_parts + bf[t] + z)              (8-way reduce in ln_res)

#define HH 8
#define TT 2048
#define EE 512
#define HT (HH * TT)
#define HE (HH * EE)

typedef __bf16 bf16_t;
typedef __attribute__((ext_vector_type(8))) __bf16 bf16x8;
typedef __attribute__((ext_vector_type(4))) float f32x4;

__device__ __forceinline__ void gld_lds16(const bf16_t* __restrict__ g, bf16_t* l) {
  __builtin_amdgcn_global_load_lds(
      (const __attribute__((address_space(1))) unsigned int*)g,
      (__attribute__((address_space(3))) unsigned int*)l, 16, 0, 0);
}

__device__ __forceinline__ bf16x8 cvt8(float4 u, float4 v) {
  bf16x8 o;
  o[0] = (__bf16)u.x; o[1] = (__bf16)u.y; o[2] = (__bf16)u.z; o[3] = (__bf16)u.w;
  o[4] = (__bf16)v.x; o[5] = (__bf16)v.y; o[6] = (__bf16)v.z; o[7] = (__bf16)v.w;
  return o;
}

// T1 XCD-bijective swizzle (m204): decode (bx,by,z) from remapped linear id.
#define XCD_SWIZZLE()                                                              \
  const int gx = gridDim.x, gy = gridDim.y;                                        \
  const int nwg = gx * gy * (int)gridDim.z;                                        \
  const int lin = blockIdx.x + gx * (blockIdx.y + gy * blockIdx.z);                \
  const int qn_ = nwg >> 3, rn_ = nwg & 7;                                         \
  const int xcd_ = lin & 7, sub_ = lin >> 3;                                       \
  const int wgid =                                                                 \
      (xcd_ < rn_ ? xcd_ * (qn_ + 1) : rn_ * (qn_ + 1) + (xcd_ - rn_) * qn_) + sub_; \
  const int bx = wgid % gx;                                                        \
  const int t1_ = wgid / gx;                                                       \
  const int by = t1_ % gy;                                                         \
  const int z = t1_ / gy;

#define BAR __builtin_amdgcn_s_barrier()
#define SCB __builtin_amdgcn_sched_barrier(0)
#define LGKM0                                                                 \
  do {                                                                        \
    asm volatile("s_waitcnt lgkmcnt(0)" ::: "memory");                        \
    __builtin_amdgcn_sched_barrier(0);                                        \
  } while (0)
#define VMC(n)                                                                \
  do {                                                                        \
    asm volatile("s_waitcnt vmcnt(" #n ")" ::: "memory");                     \
    __builtin_amdgcn_sched_barrier(0);                                        \
  } while (0)

// =====================================================================
// 256x256 8-phase GEMM (bf16 A,B). grid (M/256, N/256, nz), 512 threads.
// K % 128 == 0. Per-z: A += z*sA, B += z*sB, C += z*sC, bias_n += z*sBN.
// (verified r4-r7; unchanged)
// =====================================================================
template <typename CT>
__global__ __launch_bounds__(512, 2) void gemm256_8ph(
    const bf16_t* __restrict__ A, const bf16_t* __restrict__ B, CT* __restrict__ C,
    const float* __restrict__ bias_n,
    int K, int lda, int ldb, int ldc,
    int64_t sA, int64_t sB, int64_t sC, int64_t sBN) {
  XCD_SWIZZLE();
  A += z * sA;
  B += z * sB;
  C += z * sC;
  if (bias_n) bias_n += z * sBN;

  const int m0 = bx * 256;
  const int n0 = by * 256;
  const int tid = threadIdx.x;

  __shared__ bf16_t lds[65536];
  bf16_t* sAl = lds;
  bf16_t* sBl = lds + 32768;

  const int srow = tid >> 3;
  const int csw = ((tid & 7) ^ (srow & 7)) * 8;
  const bf16_t* aS = A + (int64_t)(m0 + srow) * lda + csw;
  const bf16_t* bS = B + (int64_t)(n0 + srow) * ldb + csw;
  const int64_t l64a = (int64_t)64 * lda, l64b = (int64_t)64 * ldb;

  const int wave = tid >> 6, lane = tid & 63;
  const int wr = wave >> 2, wc = wave & 3;
  const int fr = lane & 15, qd = lane >> 4;
  const int aoff = wr * 8192 + fr * 64;
  const int boff = wc * 4096 + fr * 64;
  const int ck0 = ((0 * 4 + qd) ^ (fr & 7)) * 8;
  const int ck1 = ((1 * 4 + qd) ^ (fr & 7)) * 8;

  f32x4 acc[8][4];
#pragma unroll
  for (int i = 0; i < 8; i++)
#pragma unroll
    for (int j = 0; j < 4; j++) acc[i][j] = (f32x4){0.f, 0.f, 0.f, 0.f};

  bf16x8 aR[2][8];
  bf16x8 bR[2][2];

#define STG_A(d, h, t)                                                        \
  do {                                                                        \
    const bf16_t* g_ = aS + (int64_t)(h) * 128 * lda + (int64_t)(t) * 64;     \
    gld_lds16(g_, &sAl[(d) * 16384 + (h) * 8192 + tid * 8]);                  \
    gld_lds16(g_ + l64a, &sAl[(d) * 16384 + (h) * 8192 + 4096 + tid * 8]);    \
  } while (0)
#define STG_B(d, h, t)                                                        \
  do {                                                                        \
    const bf16_t* g_ = bS + (int64_t)(h) * 128 * ldb + (int64_t)(t) * 64;     \
    gld_lds16(g_, &sBl[(d) * 16384 + (h) * 8192 + tid * 8]);                  \
    gld_lds16(g_ + l64b, &sBl[(d) * 16384 + (h) * 8192 + 4096 + tid * 8]);    \
  } while (0)
#define RD_A(d, ih)                                                           \
  _Pragma("unroll") for (int i_ = 0; i_ < 4; i_++) {                          \
    const int b_ = (d) * 16384 + aoff + ((ih) * 4 + i_) * 1024;               \
    aR[0][(ih) * 4 + i_] = *(const bf16x8*)&sAl[b_ + ck0];                    \
    aR[1][(ih) * 4 + i_] = *(const bf16x8*)&sAl[b_ + ck1];                    \
  }
#define RD_B(d, jh)                                                           \
  _Pragma("unroll") for (int j_ = 0; j_ < 2; j_++) {                          \
    const int b_ = (d) * 16384 + boff + ((jh) * 2 + j_) * 1024;               \
    bR[0][j_] = *(const bf16x8*)&sBl[b_ + ck0];                               \
    bR[1][j_] = *(const bf16x8*)&sBl[b_ + ck1];                               \
  }
#define MM(qm, qn)                                                            \
  do {                                                                        \
    __builtin_amdgcn_s_setprio(1);                                            \
    _Pragma("unroll") for (int ks = 0; ks < 2; ks++)                          \
        _Pragma("unroll") for (int i_ = 0; i_ < 4; i_++)                      \
            _Pragma("unroll") for (int j_ = 0; j_ < 2; j_++)                  \
                acc[(qm) * 4 + i_][(qn) * 2 + j_] =                           \
                    __builtin_amdgcn_mfma_f32_16x16x32_bf16(                  \
                        aR[ks][(qm) * 4 + i_], bR[ks][j_],                    \
                        acc[(qm) * 4 + i_][(qn) * 2 + j_], 0, 0, 0);          \
    __builtin_amdgcn_s_setprio(0);                                            \
  } while (0)

  const int NT = K >> 6;

  STG_A(0, 0, 0); STG_A(0, 1, 0); STG_B(0, 0, 0); STG_B(0, 1, 0);
  STG_A(1, 0, 1); STG_A(1, 1, 1);
  VMC(4);
  BAR;

  for (int t0 = 0; t0 < NT; t0 += 2) {
    const int t1 = t0 + 1;
    const bool m2 = (t0 + 2) < NT;
    RD_A(0, 0); RD_B(0, 0);
    STG_B(1, 0, t1);
    BAR; LGKM0; MM(0, 0); BAR;
    RD_A(0, 1);
    STG_B(1, 1, t1);
    BAR; LGKM0; MM(1, 0); BAR;
    RD_B(0, 1);
    if (m2) STG_A(0, 0, t0 + 2);
    BAR; LGKM0; MM(0, 1); BAR;
    if (m2) STG_A(0, 1, t0 + 2);
    BAR; MM(1, 1);
    if (m2) { VMC(4); } else { VMC(0); }
    BAR;
    RD_A(1, 0); RD_B(1, 0);
    if (m2) STG_B(0, 0, t0 + 2);
    BAR; LGKM0; MM(0, 0); BAR;
    RD_A(1, 1);
    if (m2) STG_B(0, 1, t0 + 2);
    BAR; LGKM0; MM(1, 0); BAR;
    RD_B(1, 1);
    if (m2) STG_A(1, 0, t1 + 2);
    BAR; LGKM0; MM(0, 1); BAR;
    if (m2) STG_A(1, 1, t1 + 2);
    BAR; MM(1, 1);
    if (m2) VMC(4);
    BAR;
  }

#undef STG_A
#undef STG_B
#undef RD_A
#undef RD_B
#undef MM

#pragma unroll
  for (int i = 0; i < 8; i++) {
    const int row0 = m0 + wr * 128 + i * 16 + qd * 4;
#pragma unroll
    for (int j = 0; j < 4; j++) {
      const int col = n0 + wc * 64 + j * 16 + fr;
      const float bn = bias_n ? bias_n[col] : 0.f;
#pragma unroll
      for (int r = 0; r < 4; r++)
        C[(int64_t)(row0 + r) * ldc + col] = (CT)(acc[i][j][r] + bn);
    }
  }
}

// =====================================================================
// 128x128 2-phase dbuf GEMM with COUNTED vmcnt (r8 T4 upgrade).
// grid (M/128, N/128, nz), 512 threads. K % 128 == 0.
// bf16 path: 4 vmem/phase; {STAGE(next); vmcnt(4); bar; COMPUTE(cur); bar}.
// f32-A path: 6 vmem/phase + A ds_writes;
//   {LOAD_A(next); STAGE_B(next); vmcnt(6); bar; COMPUTE(cur);
//    vmcnt(2); WRITE_A(next); lgkmcnt(0); bar}.
// Steady-state invariant (f32): 2 B-loads outstanding across phase boundary.
// =====================================================================
template <typename AT, typename CT>
__global__ __launch_bounds__(512, 4) void mfma_gemm_nt(
    const AT* __restrict__ A, const bf16_t* __restrict__ B, CT* __restrict__ C,
    const float* __restrict__ bias_m, const float* __restrict__ bias_n,
    int K, int lda, int ldb, int ldc,
    int64_t sA, int64_t sB, int64_t sC, int64_t sBM, int64_t sBN) {
  XCD_SWIZZLE();
  A += z * sA;
  B += z * sB;
  C += z * sC;
  if (bias_m) bias_m += z * sBM;
  if (bias_n) bias_n += z * sBN;

  const int m0 = bx * 128;
  const int n0 = by * 128;
  const int tid = threadIdx.x;

  __shared__ bf16_t sAb[2][128 * 64];
  __shared__ bf16_t sBb[2][128 * 64];

  const int srow = tid >> 3;
  const int sc = tid & 7;
  const int csw = (sc ^ (srow & 7)) * 8;
  const AT* a0 = A + (int64_t)(m0 + srow) * lda + csw;
  const AT* a1 = a0 + (int64_t)64 * lda;
  const bf16_t* b0 = B + (int64_t)(n0 + srow) * ldb + csw;
  const bf16_t* b1 = b0 + (int64_t)64 * ldb;

  const int wave = tid >> 6;
  const int lane = tid & 63;
  const int wm = (wave >> 2) * 64;
  const int wn = (wave & 3) * 32;
  const int fr = lane & 15;
  const int qd = lane >> 4;
  const int cx0 = ((0 * 4 + qd) ^ (fr & 7)) * 8;
  const int cx1 = ((1 * 4 + qd) ^ (fr & 7)) * 8;

  f32x4 acc[4][2];
#pragma unroll
  for (int i = 0; i < 4; i++)
#pragma unroll
    for (int j = 0; j < 2; j++) acc[i][j] = (f32x4){0.f, 0.f, 0.f, 0.f};

  float4 pa[4];

#define STAGE_B(buf, kt)                              \
  do {                                                \
    gld_lds16(b0 + (kt), &sBb[buf][tid * 8]);         \
    gld_lds16(b1 + (kt), &sBb[buf][4096 + tid * 8]);  \
  } while (0)
#define STAGE_A_BF16(buf, kt)                         \
  do {                                                \
    gld_lds16(a0 + (kt), &sAb[buf][tid * 8]);         \
    gld_lds16(a1 + (kt), &sAb[buf][4096 + tid * 8]);  \
  } while (0)
#define LOAD_A_F32(kt)                                \
  do {                                                \
    pa[0] = ((const float4*)(a0 + (kt)))[0];          \
    pa[1] = ((const float4*)(a0 + (kt)))[1];          \
    pa[2] = ((const float4*)(a1 + (kt)))[0];          \
    pa[3] = ((const float4*)(a1 + (kt)))[1];          \
  } while (0)
#define WRITE_A_F32(buf)                                      \
  do {                                                        \
    *(bf16x8*)&sAb[buf][tid * 8] = cvt8(pa[0], pa[1]);        \
    *(bf16x8*)&sAb[buf][4096 + tid * 8] = cvt8(pa[2], pa[3]); \
  } while (0)
#define COMPUTE(buf)                                                                   \
  do {                                                                                 \
    bf16x8 af[2][4], bfr[2][2];                                                        \
    _Pragma("unroll") for (int i = 0; i < 4; i++) {                                    \
      const int ar = (wm + i * 16 + fr) * 64;                                          \
      af[0][i] = *(const bf16x8*)&sAb[buf][ar + cx0];                                  \
      af[1][i] = *(const bf16x8*)&sAb[buf][ar + cx1];                                  \
    }                                                                                  \
    _Pragma("unroll") for (int j = 0; j < 2; j++) {                                    \
      const int br = (wn + j * 16 + fr) * 64;                                          \
      bfr[0][j] = *(const bf16x8*)&sBb[buf][br + cx0];                                 \
      bfr[1][j] = *(const bf16x8*)&sBb[buf][br + cx1];                                 \
    }                                                                                  \
    _Pragma("unroll") for (int ks = 0; ks < 2; ks++)                                   \
        _Pragma("unroll") for (int i = 0; i < 4; i++)                                  \
            _Pragma("unroll") for (int j = 0; j < 2; j++)                              \
                acc[i][j] = __builtin_amdgcn_mfma_f32_16x16x32_bf16(                   \
                    af[ks][i], bfr[ks][j], acc[i][j], 0, 0, 0);                        \
  } while (0)

  if constexpr (sizeof(AT) == 2) {
    // ---- bf16 path: counted-vmcnt 2ph ----
    // prologue: tile0 -> buf0 (4 vmem out; no wait/barrier needed yet)
    STAGE_A_BF16(0, 0);
    STAGE_B(0, 0);
    for (int kt = 0; kt < K; kt += 128) {
      // phase A: stage tile(kt+64)->buf1; compute buf0
      STAGE_A_BF16(1, kt + 64);
      STAGE_B(1, kt + 64);
      VMC(4);        // buf0's 4 loads retired; buf1's 4 in flight
      BAR; SCB;
      COMPUTE(0);
      BAR;           // readers of buf0 done before next re-stage
      // phase B: stage tile(kt+128)->buf0 (if any); compute buf1
      const bool more = (kt + 128) < K;
      if (more) {
        STAGE_A_BF16(0, kt + 128);
        STAGE_B(0, kt + 128);
        VMC(4);
      } else {
        VMC(0);
      }
      BAR; SCB;
      COMPUTE(1);
      BAR;
    }
  } else {
    // ---- f32-A path: counted-vmcnt 2ph with T14 reg-staged A ----
    // prologue: A0->regs, B0 gld (6 vmem); vmcnt(2) retires A0; write A0; lgkm0.
    LOAD_A_F32(0);
    STAGE_B(0, 0);
    VMC(2);
    WRITE_A_F32(0);
    LGKM0;           // end-state: 2 B-loads outstanding
    for (int kt = 0; kt < K; kt += 128) {
      // phase A: issue tile(kt+64) {A->regs, B->buf1}; compute buf0
      LOAD_A_F32(kt + 64);
      STAGE_B(1, kt + 64);
      VMC(6);        // retires B(cur)=2 oldest; A(next)4+B(next)2 in flight
      BAR; SCB;
      COMPUTE(0);
      VMC(2);        // retires A(next)4; B(next)2 in flight
      WRITE_A_F32(1);
      LGKM0;
      BAR;
      // phase B
      const bool more = (kt + 128) < K;
      if (more) {
        LOAD_A_F32(kt + 128);
        STAGE_B(0, kt + 128);
        VMC(6);
      } else {
        VMC(0);
      }
      BAR; SCB;
      COMPUTE(1);
      if (more) {
        VMC(2);
        WRITE_A_F32(0);
        LGKM0;
      }
      BAR;
    }
  }

#undef STAGE_B
#undef STAGE_A_BF16
#undef LOAD_A_F32
#undef WRITE_A_F32
#undef COMPUTE

#pragma unroll
  for (int i = 0; i < 4; i++) {
    const int row0 = m0 + wm + i * 16 + qd * 4;
#pragma unroll
    for (int j = 0; j < 2; j++) {
      const int col = n0 + wn + j * 16 + fr;
      const float bn = bias_n ? bias_n[col] : 0.f;
#pragma unroll
      for (int r = 0; r < 4; r++) {
        const float bm = bias_m ? bias_m[row0 + r] : 0.f;
        C[(int64_t)(row0 + r) * ldc + col] = (CT)(acc[i][j][r] + bn + bm);
      }
    }
  }
}

// ---------- fused f32 -> bf16 convert: x,y,z,Wq,Wk,Wv in ONE launch ----------
__global__ __launch_bounds__(256) void fused_cvt(
    const float* __restrict__ x, const float* __restrict__ y,
    const float* __restrict__ z, const float* __restrict__ Wq,
    const float* __restrict__ Wk, const float* __restrict__ Wv,
    bf16_t* __restrict__ xb, bf16_t* __restrict__ yb, bf16_t* __restrict__ zb,
    bf16_t* __restrict__ Wqb, bf16_t* __restrict__ Wkb, bf16_t* __restrict__ Wvb) {
  const int b = blockIdx.x;
  const float* s;
  bf16_t* d;
  int off;
  if (b < 512) { s = x; d = xb; off = b; }
  else if (b < 1024) { s = y; d = yb; off = b - 512; }
  else if (b < 1536) { s = z; d = zb; off = b - 1024; }
  else if (b < 2560) { s = Wq; d = Wqb; off = b - 1536; }
  else if (b < 3584) { s = Wk; d = Wkb; off = b - 2560; }
  else { s = Wv; d = Wvb; off = b - 3584; }
  const int64_t i = ((int64_t)off * 256 + threadIdx.x) * 8;
  float4 u = ((const float4*)(s + i))[0];
  float4 v = ((const float4*)(s + i))[1];
  *(bf16x8*)(d + i) = cvt8(u, v);
}

// ---------- in-place row softmax (rows of length T), 1/sqrt(T) pre-scale ----------
__global__ __launch_bounds__(256) void softmax_rows(bf16_t* __restrict__ S) {
  const float scale = 0.022097086912079608f;  // 1/sqrt(2048)
  bf16_t* p = S + (int64_t)blockIdx.x * TT;
  const int tid = threadIdx.x;
  bf16x8 in = *(const bf16x8*)(p + tid * 8);
  float v[8];
  float mx = -1e30f;
#pragma unroll
  for (int i = 0; i < 8; i++) {
    v[i] = (float)in[i] * scale;
    mx = fmaxf(mx, v[i]);
  }
#pragma unroll
  for (int o = 32; o > 0; o >>= 1) mx = fmaxf(mx, __shfl_xor(mx, o));
  __shared__ float redm[4], reds[4];
  if ((tid & 63) == 0) redm[tid >> 6] = mx;
  __syncthreads();
  mx = fmaxf(fmaxf(redm[0], redm[1]), fmaxf(redm[2], redm[3]));
  float sum = 0.f;
#pragma unroll
  for (int i = 0; i < 8; i++) {
    v[i] = __expf(v[i] - mx);
    sum += v[i];
  }
#pragma unroll
  for (int o = 32; o > 0; o >>= 1) sum += __shfl_xor(sum, o);
  if ((tid & 63) == 0) reds[tid >> 6] = sum;
  __syncthreads();
  sum = reds[0] + reds[1] + reds[2] + reds[3];
  const float inv = 1.0f / sum;
  bf16x8 o8;
#pragma unroll
  for (int i = 0; i < 8; i++) o8[i] = (__bf16)(v[i] * inv);
  *(bf16x8*)(p + tid * 8) = o8;
}

// ---------- out = LN(sum_{pz<np} fin_parts + bf[t] + z), eps=1e-4, population var ----
__global__ __launch_bounds__(256) void ln_res(const float* __restrict__ F,
                                              const float* __restrict__ Z,
                                              const float* __restrict__ BF,
                                              float* __restrict__ O, int np) {
  const int row = blockIdx.x;
  const int tid = threadIdx.x;
  const int64_t off = (int64_t)row * EE + tid;
  float a = 0.f, b = 0.f;
  for (int pz = 0; pz < np; pz++) {
    const float* f = F + (int64_t)pz * TT * EE;
    a += f[off];
    b += f[off + 256];
  }
  const float bft = BF[row];
  a += bft + Z[off];
  b += bft + Z[off + 256];
  float s = a + b, ss = a * a + b * b;
#pragma unroll
  for (int w = 32; w > 0; w >>= 1) {
    s += __shfl_xor(s, w);
    ss += __shfl_xor(ss, w);
  }
  __shared__ float rs[4], rss[4];
  if ((tid & 63) == 0) {
    rs[tid >> 6] = s;
    rss[tid >> 6] = ss;
  }
  __syncthreads();
  s = rs[0] + rs[1] + rs[2] + rs[3];
  ss = rss[0] + rss[1] + rss[2] + rss[3];
  const float mean = s * (1.0f / EE);
  const float var = ss * (1.0f / EE) - mean * mean;
  const float inv = rsqrtf(var + 1e-4f);
  float* o = O + (int64_t)row * EE;
  o[tid] = (a - mean) * inv;
  o[tid + 256] = (b - mean) * inv;
}

extern "C" void kernel_launch(void* const* d_in, const int* in_sizes, int n_in,
                              void* d_out, int out_size, void* d_ws, size_t ws_size,
                              hipStream_t stream) {
  const float* x = (const float*)d_in[0];
  const float* y = (const float*)d_in[1];
  const float* z = (const float*)d_in[2];
  const float* Wq = (const float*)d_in[3];
  const float* bq = (const float*)d_in[4];
  const float* Wk = (const float*)d_in[5];
  const float* bk = (const float*)d_in[6];
  const float* Wv = (const float*)d_in[7];
  const float* bv = (const float*)d_in[8];
  const float* Wf = (const float*)d_in[9];
  const float* bfb = (const float*)d_in[10];
  float* out = (float*)d_out;

  const size_t MB = 1ull << 20;
  char* p = (char*)d_ws;

  if (ws_size >= 151 * MB) {
    // ---- FULL layout (head-batched) ----
    bf16_t* xb = (bf16_t*)(p + 0 * MB);
    bf16_t* yb = (bf16_t*)(p + 2 * MB);
    bf16_t* zb = (bf16_t*)(p + 4 * MB);
    bf16_t* Wqb = (bf16_t*)(p + 6 * MB);
    bf16_t* Wkb = (bf16_t*)(p + 10 * MB);
    bf16_t* Wvb = (bf16_t*)(p + 14 * MB);
    bf16_t* q = (bf16_t*)(p + 18 * MB);     // [T][H*E]
    bf16_t* k = (bf16_t*)(p + 34 * MB);     // [T][H*E]
    bf16_t* vT = (bf16_t*)(p + 50 * MB);    // [8][E][T]
    bf16_t* att = (bf16_t*)(p + 66 * MB);   // [8][T][T] (64 MB; dead after hoT)
    bf16_t* hoT = (bf16_t*)(p + 130 * MB);  // [E][H*T]
    float* finp = (float*)(p + 66 * MB);    // [8][T][E] f32 (overlays dead att)

    fused_cvt<<<4608, 256, 0, stream>>>(x, y, z, Wq, Wk, Wv, xb, yb, zb, Wqb, Wkb, Wvb);

    // q_all[T][HE] = x @ Wq_cat^T + bq_flat  (heads stacked along N)
    mfma_gemm_nt<bf16_t, bf16_t><<<dim3(16, 32, 1), 512, 0, stream>>>(
        xb, Wqb, q, nullptr, bq, EE, EE, EE, HE, 0, 0, 0, 0, 0);
    mfma_gemm_nt<bf16_t, bf16_t><<<dim3(16, 32, 1), 512, 0, stream>>>(
        yb, Wkb, k, nullptr, bk, EE, EE, EE, HE, 0, 0, 0, 0, 0);
    // vT[h*E+f][t] = Wv_cat[h*E+f][:] . z[t][:] + bv_flat  -> [8][E][T]
    mfma_gemm_nt<bf16_t, bf16_t><<<dim3(32, 16, 1), 512, 0, stream>>>(
        Wvb, zb, vT, bv, nullptr, EE, EE, EE, TT, 0, 0, 0, 0, 0);
    // att[h][s][t] = q_all[s][hE:+E] . k_all[t][hE:+E]  (8-phase engine, 512 wgs)
    gemm256_8ph<bf16_t><<<dim3(8, 8, 8), 512, 0, stream>>>(
        q, k, att, nullptr, EE, HE, HE, TT, EE, EE, (int64_t)TT * TT, 0);
    softmax_rows<<<HH * TT, 256, 0, stream>>>(att);
    // hoT[f][h*T+s] = vT[h][f][:] . att[h][s][:]
    mfma_gemm_nt<bf16_t, bf16_t><<<dim3(4, 16, 8), 512, 0, stream>>>(
        vT, att, hoT, nullptr, nullptr, TT, TT, TT, HT, (int64_t)EE * TT, (int64_t)TT * TT,
        (int64_t)TT, 0, 0);
    // fin_parts[z][t][e] = Wf[t][zK:+K] . hoT[e][zK:+K]  (split-K=8, r6 config)
    mfma_gemm_nt<float, float><<<dim3(16, 4, 8), 512, 0, stream>>>(
        Wf, hoT, finp, nullptr, nullptr, HT / 8, HT, HT, EE, HT / 8, HT / 8,
        (int64_t)TT * EE, 0, 0);
    ln_res<<<TT, 256, 0, stream>>>(finp, z, bfb, out, 8);
  } else {
    // ---- LEAN layout (per-head) ----
    bf16_t* xb = (bf16_t*)(p + 0 * MB);
    bf16_t* yb = (bf16_t*)(p + 2 * MB);
    bf16_t* zb = (bf16_t*)(p + 4 * MB);
    bf16_t* Wqb = (bf16_t*)(p + 6 * MB);
    bf16_t* Wkb = (bf16_t*)(p + 10 * MB);
    bf16_t* Wvb = (bf16_t*)(p + 14 * MB);
    bf16_t* qh = (bf16_t*)(p + 18 * MB);
    bf16_t* kh = (bf16_t*)(p + 20 * MB);
    bf16_t* vTh = (bf16_t*)(p + 22 * MB);
    bf16_t* att = (bf16_t*)(p + 24 * MB);
    bf16_t* hoT = (bf16_t*)(p + 32 * MB);
    float* finp = (float*)(p + 0 * MB);

    fused_cvt<<<4608, 256, 0, stream>>>(x, y, z, Wq, Wk, Wv, xb, yb, zb, Wqb, Wkb, Wvb);

    for (int h = 0; h < HH; h++) {
      const bf16_t* Wq_h = Wqb + (int64_t)h * EE * EE;
      const bf16_t* Wk_h = Wkb + (int64_t)h * EE * EE;
      const bf16_t* Wv_h = Wvb + (int64_t)h * EE * EE;
      mfma_gemm_nt<bf16_t, bf16_t><<<dim3(16, 4, 1), 512, 0, stream>>>(
          xb, Wq_h, qh, nullptr, bq + h * EE, EE, EE, EE, EE, 0, 0, 0, 0, 0);
      mfma_gemm_nt<bf16_t, bf16_t><<<dim3(16, 4, 1), 512, 0, stream>>>(
          yb, Wk_h, kh, nullptr, bk + h * EE, EE, EE, EE, EE, 0, 0, 0, 0, 0);
      mfma_gemm_nt<bf16_t, bf16_t><<<dim3(4, 16, 1), 512, 0, stream>>>(
          Wv_h, zb, vTh, bv + h * EE, nullptr, EE, EE, EE, TT, 0, 0, 0, 0, 0);
      mfma_gemm_nt<bf16_t, bf16_t><<<dim3(16, 16, 1), 512, 0, stream>>>(
          qh, kh, att, nullptr, nullptr, EE, EE, EE, TT, 0, 0, 0, 0, 0);
      softmax_rows<<<TT, 256, 0, stream>>>(att);
      mfma_gemm_nt<bf16_t, bf16_t><<<dim3(4, 16, 1), 512, 0, stream>>>(
          vTh, att, hoT + (int64_t)h * TT, nullptr, nullptr, TT, TT, TT, HT, 0, 0, 0, 0, 0);
    }
    mfma_gemm_nt<float, float><<<dim3(16, 4, 8), 512, 0, stream>>>(
        Wf, hoT, finp, nullptr, nullptr, HT / 8, HT, HT, EE, HT / 8, HT / 8,
        (int64_t)TT * EE, 0, 0);
    ln_res<<<TT, 256, 0, stream>>>(finp, z, bfb, out, 8);
  }
}